// Round 1
// baseline (791.046 us; speedup 1.0000x reference)
//
#include <hip/hip_runtime.h>

#define BIGF 3.402823466e38f

__device__ __forceinline__ void gload_lds16(const float* g, float* lds) {
  __builtin_amdgcn_global_load_lds((const __attribute__((address_space(1))) void*)g,
                                   (__attribute__((address_space(3))) void*)lds, 16, 0, 0);
}

// ---------------- K1: transpose + sq + y (x@w1^T) + delta (z - y) ----------------
__global__ __launch_bounds__(256) void k1_pre(const float* __restrict__ x, const float* __restrict__ w,
                                              float* __restrict__ sq, float* __restrict__ y,
                                              float* __restrict__ delta) {
  __shared__ __align__(16) float xt[64][68];
  __shared__ __align__(16) float ws[128][64];
  const int t = threadIdx.x;
  const int bid = blockIdx.x;
  const int b = bid >> 6;
  const int n0 = (bid & 63) << 6;
  const float* xb = x + (size_t)b * 64 * 4096;

#pragma unroll
  for (int rep = 0; rep < 16; ++rep) {
    int id = rep * 256 + t;
    int d = id >> 6, n = id & 63;
    xt[n][d] = xb[(size_t)d * 4096 + n0 + n];
  }
#pragma unroll
  for (int rep = 0; rep < 32; ++rep) {
    int id = rep * 256 + t;
    int u = id >> 6, dd = id & 63;
    ws[u][dd] = w[(u & 63) * 128 + ((u >> 6) << 6) + dd];
  }
  __syncthreads();

  const int p = t & 63;
  const int oc = t >> 6;  // each thread: 16 output channels, both y and z
  float accy[16], accz[16];
#pragma unroll
  for (int j = 0; j < 16; ++j) { accy[j] = 0.f; accz[j] = 0.f; }

#pragma unroll 4
  for (int d4 = 0; d4 < 16; ++d4) {
    const float4 xv = *(const float4*)&xt[p][d4 * 4];
#pragma unroll
    for (int j = 0; j < 16; ++j) {
      const int o = oc * 16 + j;
      const float4 wy = *(const float4*)&ws[o][d4 * 4];
      const float4 wz = *(const float4*)&ws[o + 64][d4 * 4];
      accy[j] = fmaf(xv.x, wy.x, fmaf(xv.y, wy.y, fmaf(xv.z, wy.z, fmaf(xv.w, wy.w, accy[j]))));
      accz[j] = fmaf(xv.x, wz.x, fmaf(xv.y, wz.y, fmaf(xv.z, wz.z, fmaf(xv.w, wz.w, accz[j]))));
    }
  }

  if (oc == 0) {
    float s = 0.f;
#pragma unroll
    for (int d4 = 0; d4 < 16; ++d4) {
      const float4 v = *(const float4*)&xt[p][d4 * 4];
      s = fmaf(v.x, v.x, fmaf(v.y, v.y, fmaf(v.z, v.z, fmaf(v.w, v.w, s))));
    }
    sq[b * 4096 + n0 + p] = s;
  }

  const size_t row = ((size_t)b * 4096 + n0 + p) * 64 + oc * 16;
#pragma unroll
  for (int j4 = 0; j4 < 4; ++j4) {
    float4 yv = make_float4(accy[j4 * 4], accy[j4 * 4 + 1], accy[j4 * 4 + 2], accy[j4 * 4 + 3]);
    float4 dv = make_float4(accz[j4 * 4] - accy[j4 * 4], accz[j4 * 4 + 1] - accy[j4 * 4 + 1],
                            accz[j4 * 4 + 2] - accy[j4 * 4 + 2], accz[j4 * 4 + 3] - accy[j4 * 4 + 3]);
    *(float4*)&y[row + j4 * 4] = yv;
    *(float4*)&delta[row + j4 * 4] = dv;
  }
}

// ---------------- K2: fused pairwise-distance GEMM + streaming top-20 ----------------
// block = 256 thr (4 waves), 64-point n-tile. A (64d x 64n) shared; each wave owns an
// 8KB LDS slice cycling: B-stage (64d x 32m) -> GEMM -> C-dump (64n x 32m, XOR-swizzled)
// -> scan. No barriers in the main loop.
__global__ __launch_bounds__(256, 2) void k2_knn(const float* __restrict__ x,
                                                 const float* __restrict__ sq,
                                                 int* __restrict__ idx_out) {
  __shared__ __align__(16) float smem[4096 + 4 * 2048];  // As(16KB) + 4x8KB wave slices
  float* As = smem;
  const int t = threadIdx.x;
  const int lane = t & 63;
  const int w = t >> 6;
  float* BsW = smem + 4096 + (w << 11);

  const int bid = blockIdx.x;
  const int b = bid >> 6;
  const int n0 = (bid & 63) << 6;
  const int ln = lane >> 3, lm = lane & 7;

  const float* xb = x + (size_t)b * 64 * 4096;
  const float* sqb = sq + b * 4096;

  // stage A tile: 16 x 1KB global_load_lds, 4 per wave. layout (d, n)
  {
    const int dr = lane >> 4;
    const int c4 = (lane & 15) << 2;
#pragma unroll
    for (int q = 0; q < 4; ++q) {
      const int k = w * 4 + q;
      gload_lds16(xb + (size_t)(k * 4 + dr) * 4096 + n0 + c4, As + k * 256);
    }
  }
  __syncthreads();

  // per-lane top-20 (scan role: local point n = lane), sorted ascending
  float kd[20];
  int ki[20];
#pragma unroll
  for (int s = 0; s < 20; ++s) { kd[s] = BIGF; ki[s] = -1; }
  const float sqn = sqb[n0 + lane];
  const int myn = lane;
  const int swz = myn & 7;

  auto ins = [&](float vd, int vi) {
#pragma unroll
    for (int s = 0; s < 20; ++s) {
      const float od = kd[s];
      const int oi = ki[s];
      const bool lt = vd < od;
      kd[s] = lt ? vd : od;
      ki[s] = lt ? vi : oi;
      vd = lt ? od : vd;
      vi = lt ? oi : vi;
    }
  };

  for (int kt = 0; kt < 32; ++kt) {
    const int mbase = (w + 4 * kt) << 5;  // 32-wide m tile, wave-strided
    // stage B tile (64d x 32m) into this wave's slice: 8 x 1KB
    {
      const int dr = lane >> 3;
      const int c4 = (lane & 7) << 2;
#pragma unroll
      for (int k = 0; k < 8; ++k) {
        gload_lds16(xb + (size_t)(k * 8 + dr) * 4096 + mbase + c4, BsW + k * 256);
      }
    }
    const float4 sqm = *(const float4*)&sqb[mbase + lm * 4];
    __builtin_amdgcn_s_waitcnt(0x0F70);  // vmcnt(0)

    // GEMM: 8n x 4m fragment per lane over 64 d-steps
    float acc[8][4];
#pragma unroll
    for (int i = 0; i < 8; ++i)
#pragma unroll
      for (int j = 0; j < 4; ++j) acc[i][j] = 0.f;

#pragma unroll 8
    for (int d = 0; d < 64; ++d) {
      const float4 a0 = *(const float4*)&As[(d << 6) + (ln << 3)];
      const float4 a1 = *(const float4*)&As[(d << 6) + (ln << 3) + 4];
      const float4 bb = *(const float4*)&BsW[(d << 5) + (lm << 2)];
      const float av[8] = {a0.x, a0.y, a0.z, a0.w, a1.x, a1.y, a1.z, a1.w};
      const float bv[4] = {bb.x, bb.y, bb.z, bb.w};
#pragma unroll
      for (int i = 0; i < 8; ++i)
#pragma unroll
        for (int j = 0; j < 4; ++j) acc[i][j] = fmaf(av[i], bv[j], acc[i][j]);
    }

    // dump (sq_m - 2*dot) into own slice, XOR-swizzled chunks (conflict-free)
    const float sqmv[4] = {sqm.x, sqm.y, sqm.z, sqm.w};
#pragma unroll
    for (int i = 0; i < 8; ++i) {
      const int n = (ln << 3) + i;
      const int pc = lm ^ (n & 7);
      float4 v;
      v.x = fmaf(-2.f, acc[i][0], sqmv[0]);
      v.y = fmaf(-2.f, acc[i][1], sqmv[1]);
      v.z = fmaf(-2.f, acc[i][2], sqmv[2]);
      v.w = fmaf(-2.f, acc[i][3], sqmv[3]);
      *(float4*)&BsW[(n << 5) + (pc << 2)] = v;
    }

    // scan own row: 8 chunks of 4, min4 pre-gate then guarded inserts (m ascending)
#pragma unroll 1
    for (int cc = 0; cc < 8; ++cc) {
      const float4 v = *(const float4*)&BsW[(myn << 5) + ((cc ^ swz) << 2)];
      const int mb = mbase + (cc << 2);
      const float c0 = sqn + v.x, c1 = sqn + v.y, c2 = sqn + v.z, c3 = sqn + v.w;
      const float mn = fminf(fminf(c0, c1), fminf(c2, c3));
      if (mn < kd[19]) {
        if (c0 < kd[19]) ins(c0, mb);
        if (c1 < kd[19]) ins(c1, mb + 1);
        if (c2 < kd[19]) ins(c2, mb + 2);
        if (c3 < kd[19]) ins(c3, mb + 3);
      }
    }
  }

  // merge the 4 waves' partial lists (LDS overlay on smem)
  __syncthreads();
  float* pf = smem;                 // [4][20][64]
  int* pi = (int*)(smem + 5120);    // [4][20][64]
#pragma unroll
  for (int s = 0; s < 20; ++s) {
    pf[(w * 20 + s) * 64 + lane] = kd[s];
    pi[(w * 20 + s) * 64 + lane] = ki[s];
  }
  __syncthreads();
  if (w == 0) {
    auto insTie = [&](float vd, int vi) {
#pragma unroll
      for (int s = 0; s < 20; ++s) {
        const float od = kd[s];
        const int oi = ki[s];
        const bool lt = (vd < od) || (vd == od && vi < oi);
        kd[s] = lt ? vd : od;
        ki[s] = lt ? vi : oi;
        vd = lt ? od : vd;
        vi = lt ? oi : vi;
      }
    };
    for (int ww = 1; ww < 4; ++ww) {
#pragma unroll 1
      for (int s = 0; s < 20; ++s) {
        const float dv = pf[(ww * 20 + s) * 64 + lane];
        const int iv = pi[(ww * 20 + s) * 64 + lane];
        if (dv < kd[19] || (dv == kd[19] && iv < ki[19])) insTie(dv, iv);
      }
    }
    int* orow = idx_out + ((size_t)b * 4096 + n0 + lane) * 20;
#pragma unroll
    for (int s = 0; s < 20; ++s) orow[s] = ki[s];
  }
}

// ---------------- K3: gathered neighbor max + h + BN stats ----------------
__global__ __launch_bounds__(256) void k3_gather(const float* __restrict__ y,
                                                 const float* __restrict__ delta,
                                                 const int* __restrict__ idx,
                                                 float* __restrict__ h,
                                                 float* __restrict__ sums,
                                                 float* __restrict__ sumsq) {
  const int t = threadIdx.x;
  const int lane = t & 63;  // channel o
  const int w = t >> 6;
  const int blk = blockIdx.x;  // 512 blocks x 64 points
  float s1 = 0.f, s2 = 0.f;
  for (int p = 0; p < 16; ++p) {
    const int ng = blk * 64 + w * 16 + p;  // global point id
    const int b = ng >> 12;
    const int* row = idx + (size_t)ng * 20;
    float mx = -BIGF;
#pragma unroll
    for (int kk = 0; kk < 20; ++kk) {
      const int nbr = row[kk];
      mx = fmaxf(mx, y[((size_t)(b << 12) + nbr) * 64 + lane]);
    }
    const float hv = mx + delta[(size_t)ng * 64 + lane];
    h[(size_t)ng * 64 + lane] = hv;
    s1 += hv;
    s2 += hv * hv;
  }
  __shared__ float r1[4][64], r2[4][64];
  r1[w][lane] = s1;
  r2[w][lane] = s2;
  __syncthreads();
  if (w == 0) {
    const float a = r1[0][lane] + r1[1][lane] + r1[2][lane] + r1[3][lane];
    const float c = r2[0][lane] + r2[1][lane] + r2[2][lane] + r2[3][lane];
    atomicAdd(&sums[lane], a);
    atomicAdd(&sumsq[lane], c);
  }
}

// ---------------- K4: BN finalize + exact GELU + transposed write ----------------
__global__ __launch_bounds__(256) void k4_bn(const float* __restrict__ h,
                                             const float* __restrict__ sums,
                                             const float* __restrict__ sumsq,
                                             const float* __restrict__ gamma,
                                             const float* __restrict__ beta,
                                             float* __restrict__ out) {
  __shared__ float tile[64][65];
  const int bid = blockIdx.x;
  const int b = bid >> 6;
  const int n0 = (bid & 63) << 6;
  const int t = threadIdx.x;
  const int o = t & 63;
#pragma unroll
  for (int it = 0; it < 16; ++it) {
    const int n = (t >> 6) * 16 + it;
    tile[n][o] = h[(((size_t)b << 12) + n0 + n) * 64 + o];
  }
  __syncthreads();
  const int j = t & 63;
#pragma unroll
  for (int it = 0; it < 16; ++it) {
    const int oo = (t >> 6) * 16 + it;
    const float mean = sums[oo] * (1.0f / 32768.0f);
    const float var = sumsq[oo] * (1.0f / 32768.0f) - mean * mean;
    const float sc = gamma[oo] / sqrtf(var + 1e-5f);
    const float hv = tile[j][oo];
    const float hn = (hv - mean) * sc + beta[oo];
    const float g = 0.5f * hn * (1.0f + erff(hn * 0.70710678118654752f));
    out[((size_t)(b * 64 + oo)) * 4096 + n0 + j] = g;
  }
}

extern "C" void kernel_launch(void* const* d_in, const int* in_sizes, int n_in,
                              void* d_out, int out_size, void* d_ws, size_t ws_size,
                              hipStream_t stream) {
  const float* x = (const float*)d_in[0];
  const float* w = (const float*)d_in[1];
  const float* gamma = (const float*)d_in[2];
  const float* beta = (const float*)d_in[3];
  float* out = (float*)d_out;

  float* sq_ws = (float*)d_ws;               // 32768
  float* y_ws = sq_ws + 32768;               // 8 MB
  float* delta_ws = y_ws + 2097152;          // 8 MB
  float* h_ws = delta_ws + 2097152;          // 8 MB
  int* idx_ws = (int*)(h_ws + 2097152);      // 2.6 MB
  float* sums = (float*)(idx_ws + 655360);   // 64
  float* sumsq = sums + 64;                  // 64

  hipMemsetAsync(sums, 0, 2 * 64 * sizeof(float), stream);
  k1_pre<<<512, 256, 0, stream>>>(x, w, sq_ws, y_ws, delta_ws);
  k2_knn<<<512, 256, 0, stream>>>(x, sq_ws, idx_ws);
  k3_gather<<<512, 256, 0, stream>>>(y_ws, delta_ws, idx_ws, h_ws, sums, sumsq);
  k4_bn<<<512, 256, 0, stream>>>(h_ws, sums, sumsq, gamma, beta, out);
}

// Round 2
// 495.741 us; speedup vs baseline: 1.5957x; 1.5957x over previous
//
#include <hip/hip_runtime.h>

#define BIGF 3.402823466e38f

__device__ __forceinline__ void gload_lds16(const float* g, float* lds) {
  __builtin_amdgcn_global_load_lds((const __attribute__((address_space(1))) void*)g,
                                   (__attribute__((address_space(3))) void*)lds, 16, 0, 0);
}

// ---------------- K1: transpose + sq + y (x@w1^T) + delta (z - y) ----------------
__global__ __launch_bounds__(256) void k1_pre(const float* __restrict__ x, const float* __restrict__ w,
                                              float* __restrict__ sq, float* __restrict__ y,
                                              float* __restrict__ delta) {
  __shared__ __align__(16) float xt[64][68];
  __shared__ __align__(16) float ws[128][64];
  const int t = threadIdx.x;
  const int bid = blockIdx.x;
  const int b = bid >> 6;
  const int n0 = (bid & 63) << 6;
  const float* xb = x + (size_t)b * 64 * 4096;

#pragma unroll
  for (int rep = 0; rep < 16; ++rep) {
    int id = rep * 256 + t;
    int d = id >> 6, n = id & 63;
    xt[n][d] = xb[(size_t)d * 4096 + n0 + n];
  }
#pragma unroll
  for (int rep = 0; rep < 32; ++rep) {
    int id = rep * 256 + t;
    int u = id >> 6, dd = id & 63;
    ws[u][dd] = w[(u & 63) * 128 + ((u >> 6) << 6) + dd];
  }
  __syncthreads();

  const int p = t & 63;
  const int oc = t >> 6;  // each thread: 16 output channels, both y and z
  float accy[16], accz[16];
#pragma unroll
  for (int j = 0; j < 16; ++j) { accy[j] = 0.f; accz[j] = 0.f; }

#pragma unroll 4
  for (int d4 = 0; d4 < 16; ++d4) {
    const float4 xv = *(const float4*)&xt[p][d4 * 4];
#pragma unroll
    for (int j = 0; j < 16; ++j) {
      const int o = oc * 16 + j;
      const float4 wy = *(const float4*)&ws[o][d4 * 4];
      const float4 wz = *(const float4*)&ws[o + 64][d4 * 4];
      accy[j] = fmaf(xv.x, wy.x, fmaf(xv.y, wy.y, fmaf(xv.z, wy.z, fmaf(xv.w, wy.w, accy[j]))));
      accz[j] = fmaf(xv.x, wz.x, fmaf(xv.y, wz.y, fmaf(xv.z, wz.z, fmaf(xv.w, wz.w, accz[j]))));
    }
  }

  if (oc == 0) {
    float s = 0.f;
#pragma unroll
    for (int d4 = 0; d4 < 16; ++d4) {
      const float4 v = *(const float4*)&xt[p][d4 * 4];
      s = fmaf(v.x, v.x, fmaf(v.y, v.y, fmaf(v.z, v.z, fmaf(v.w, v.w, s))));
    }
    sq[b * 4096 + n0 + p] = s;
  }

  const size_t row = ((size_t)b * 4096 + n0 + p) * 64 + oc * 16;
#pragma unroll
  for (int j4 = 0; j4 < 4; ++j4) {
    float4 yv = make_float4(accy[j4 * 4], accy[j4 * 4 + 1], accy[j4 * 4 + 2], accy[j4 * 4 + 3]);
    float4 dv = make_float4(accz[j4 * 4] - accy[j4 * 4], accz[j4 * 4 + 1] - accy[j4 * 4 + 1],
                            accz[j4 * 4 + 2] - accy[j4 * 4 + 2], accz[j4 * 4 + 3] - accy[j4 * 4 + 3]);
    *(float4*)&y[row + j4 * 4] = yv;
    *(float4*)&delta[row + j4 * 4] = dv;
  }
}

// ---------------- K2: fused pairwise-distance GEMM + streaming top-20 ----------------
// block = 256 thr (4 waves), 64-point n-tile. A (64d x 64n) shared; each wave owns an
// 8KB LDS slice cycling: B-stage (64d x 32m) -> GEMM -> C-dump (64n x 32m, XOR-swizzled)
// -> scan. No barriers in the main loop. Accepted candidates go to a per-lane LDS
// buffer (8B push, predicated => cheap under divergence); the expensive 20-deep sorted
// insert runs only at drains (when any lane's buffer > 8 of 12 entries).
__global__ __launch_bounds__(256, 2) void k2_knn(const float* __restrict__ x,
                                                 const float* __restrict__ sq,
                                                 int* __restrict__ idx_out) {
  // As(16KB) + 4x8KB wave slices + 4x6KB accept buffers = 72 KB
  __shared__ __align__(16) float smem[4096 + 4 * 2048 + 4 * 1536];
  float* As = smem;
  const int t = threadIdx.x;
  const int lane = t & 63;
  const int w = t >> 6;
  float* BsW = smem + 4096 + (w << 11);
  uint2* bufL = (uint2*)(smem + 12288 + w * 1536) + lane * 12;  // 12 entries/lane

  const int bid = blockIdx.x;
  const int b = bid >> 6;
  const int n0 = (bid & 63) << 6;
  const int ln = lane >> 3, lm = lane & 7;

  const float* xb = x + (size_t)b * 64 * 4096;
  const float* sqb = sq + b * 4096;

  // stage A tile: 16 x 1KB global_load_lds, 4 per wave. layout (d, n)
  {
    const int dr = lane >> 4;
    const int c4 = (lane & 15) << 2;
#pragma unroll
    for (int q = 0; q < 4; ++q) {
      const int k = w * 4 + q;
      gload_lds16(xb + (size_t)(k * 4 + dr) * 4096 + n0 + c4, As + k * 256);
    }
  }
  __syncthreads();

  // per-lane top-20 (scan role: local point n = lane), sorted ascending
  float kd[20];
  int ki[20];
#pragma unroll
  for (int s = 0; s < 20; ++s) { kd[s] = BIGF; ki[s] = -1; }
  const float sqn = sqb[n0 + lane];
  const int myn = lane;
  const int swz = myn & 7;
  int cnt = 0;

  auto ins = [&](float vd, int vi) {
#pragma unroll
    for (int s = 0; s < 20; ++s) {
      const float od = kd[s];
      const int oi = ki[s];
      const bool lt = vd < od;
      kd[s] = lt ? vd : od;
      ki[s] = lt ? vi : oi;
      vd = lt ? od : vd;
      vi = lt ? oi : vi;
    }
  };

  auto drain = [&]() {
#pragma unroll 1
    for (int j = 0; j < 12; ++j) {
      if (!__any(j < cnt)) break;
      if (j < cnt) {
        const uint2 e = bufL[j];
        const float dv = __uint_as_float(e.x);
        if (dv < kd[19]) ins(dv, (int)e.y);
      }
    }
    cnt = 0;
  };

  for (int kt = 0; kt < 32; ++kt) {
    const int mbase = (w + 4 * kt) << 5;  // 32-wide m tile, wave-strided
    // stage B tile (64d x 32m) into this wave's slice: 8 x 1KB
    {
      const int dr = lane >> 3;
      const int c4 = (lane & 7) << 2;
#pragma unroll
      for (int k = 0; k < 8; ++k) {
        gload_lds16(xb + (size_t)(k * 8 + dr) * 4096 + mbase + c4, BsW + k * 256);
      }
    }
    const float4 sqm = *(const float4*)&sqb[mbase + lm * 4];
    __builtin_amdgcn_s_waitcnt(0x0F70);  // vmcnt(0)

    // GEMM: 8n x 4m fragment per lane over 64 d-steps
    float acc[8][4];
#pragma unroll
    for (int i = 0; i < 8; ++i)
#pragma unroll
      for (int j = 0; j < 4; ++j) acc[i][j] = 0.f;

#pragma unroll 8
    for (int d = 0; d < 64; ++d) {
      const float4 a0 = *(const float4*)&As[(d << 6) + (ln << 3)];
      const float4 a1 = *(const float4*)&As[(d << 6) + (ln << 3) + 4];
      const float4 bb = *(const float4*)&BsW[(d << 5) + (lm << 2)];
      const float av[8] = {a0.x, a0.y, a0.z, a0.w, a1.x, a1.y, a1.z, a1.w};
      const float bv[4] = {bb.x, bb.y, bb.z, bb.w};
#pragma unroll
      for (int i = 0; i < 8; ++i)
#pragma unroll
        for (int j = 0; j < 4; ++j) acc[i][j] = fmaf(av[i], bv[j], acc[i][j]);
    }

    // dump (sq_m - 2*dot) into own slice, XOR-swizzled chunks (conflict-free)
    const float sqmv[4] = {sqm.x, sqm.y, sqm.z, sqm.w};
#pragma unroll
    for (int i = 0; i < 8; ++i) {
      const int n = (ln << 3) + i;
      const int pc = lm ^ (n & 7);
      float4 v;
      v.x = fmaf(-2.f, acc[i][0], sqmv[0]);
      v.y = fmaf(-2.f, acc[i][1], sqmv[1]);
      v.z = fmaf(-2.f, acc[i][2], sqmv[2]);
      v.w = fmaf(-2.f, acc[i][3], sqmv[3]);
      *(float4*)&BsW[(n << 5) + (pc << 2)] = v;
    }

    // scan own row: 8 chunks of 4. Accepts are cheap predicated LDS pushes;
    // sorted insert happens only at drains.
#pragma unroll 1
    for (int cc = 0; cc < 8; ++cc) {
      const float4 v = *(const float4*)&BsW[(myn << 5) + ((cc ^ swz) << 2)];
      const int mb = mbase + (cc << 2);
      const float c0 = sqn + v.x, c1 = sqn + v.y, c2 = sqn + v.z, c3 = sqn + v.w;
      const float thr = kd[19];
      const float mn = fminf(fminf(c0, c1), fminf(c2, c3));
      if (mn < thr) {
        if (c0 < thr) { bufL[cnt] = make_uint2(__float_as_uint(c0), (unsigned)mb); cnt++; }
        if (c1 < thr) { bufL[cnt] = make_uint2(__float_as_uint(c1), (unsigned)(mb + 1)); cnt++; }
        if (c2 < thr) { bufL[cnt] = make_uint2(__float_as_uint(c2), (unsigned)(mb + 2)); cnt++; }
        if (c3 < thr) { bufL[cnt] = make_uint2(__float_as_uint(c3), (unsigned)(mb + 3)); cnt++; }
      }
      if (__any(cnt > 8)) drain();
    }
  }
  drain();

  // merge the 4 waves' partial lists (LDS overlay on smem)
  __syncthreads();
  float* pf = smem;                 // [4][20][64]
  int* pi = (int*)(smem + 5120);    // [4][20][64]
#pragma unroll
  for (int s = 0; s < 20; ++s) {
    pf[(w * 20 + s) * 64 + lane] = kd[s];
    pi[(w * 20 + s) * 64 + lane] = ki[s];
  }
  __syncthreads();
  if (w == 0) {
    auto insTie = [&](float vd, int vi) {
#pragma unroll
      for (int s = 0; s < 20; ++s) {
        const float od = kd[s];
        const int oi = ki[s];
        const bool lt = (vd < od) || (vd == od && vi < oi);
        kd[s] = lt ? vd : od;
        ki[s] = lt ? vi : oi;
        vd = lt ? od : vd;
        vi = lt ? oi : vi;
      }
    };
    for (int ww = 1; ww < 4; ++ww) {
#pragma unroll 1
      for (int s = 0; s < 20; ++s) {
        const float dv = pf[(ww * 20 + s) * 64 + lane];
        const int iv = pi[(ww * 20 + s) * 64 + lane];
        if (dv < kd[19] || (dv == kd[19] && iv < ki[19])) insTie(dv, iv);
      }
    }
    int* orow = idx_out + ((size_t)b * 4096 + n0 + lane) * 20;
#pragma unroll
    for (int s = 0; s < 20; ++s) orow[s] = ki[s];
  }
}

// ---------------- K3: gathered neighbor max + h + BN stats ----------------
__global__ __launch_bounds__(256) void k3_gather(const float* __restrict__ y,
                                                 const float* __restrict__ delta,
                                                 const int* __restrict__ idx,
                                                 float* __restrict__ h,
                                                 float* __restrict__ sums,
                                                 float* __restrict__ sumsq) {
  const int t = threadIdx.x;
  const int lane = t & 63;  // channel o
  const int w = t >> 6;
  const int blk = blockIdx.x;  // 512 blocks x 64 points
  float s1 = 0.f, s2 = 0.f;
  for (int p = 0; p < 16; ++p) {
    const int ng = blk * 64 + w * 16 + p;  // global point id
    const int b = ng >> 12;
    const int* row = idx + (size_t)ng * 20;
    float mx = -BIGF;
#pragma unroll
    for (int kk = 0; kk < 20; ++kk) {
      const int nbr = row[kk];
      mx = fmaxf(mx, y[((size_t)(b << 12) + nbr) * 64 + lane]);
    }
    const float hv = mx + delta[(size_t)ng * 64 + lane];
    h[(size_t)ng * 64 + lane] = hv;
    s1 += hv;
    s2 += hv * hv;
  }
  __shared__ float r1[4][64], r2[4][64];
  r1[w][lane] = s1;
  r2[w][lane] = s2;
  __syncthreads();
  if (w == 0) {
    const float a = r1[0][lane] + r1[1][lane] + r1[2][lane] + r1[3][lane];
    const float c = r2[0][lane] + r2[1][lane] + r2[2][lane] + r2[3][lane];
    atomicAdd(&sums[lane], a);
    atomicAdd(&sumsq[lane], c);
  }
}

// ---------------- K4: BN finalize + exact GELU + transposed write ----------------
__global__ __launch_bounds__(256) void k4_bn(const float* __restrict__ h,
                                             const float* __restrict__ sums,
                                             const float* __restrict__ sumsq,
                                             const float* __restrict__ gamma,
                                             const float* __restrict__ beta,
                                             float* __restrict__ out) {
  __shared__ float tile[64][65];
  const int bid = blockIdx.x;
  const int b = bid >> 6;
  const int n0 = (bid & 63) << 6;
  const int t = threadIdx.x;
  const int o = t & 63;
#pragma unroll
  for (int it = 0; it < 16; ++it) {
    const int n = (t >> 6) * 16 + it;
    tile[n][o] = h[(((size_t)b << 12) + n0 + n) * 64 + o];
  }
  __syncthreads();
  const int j = t & 63;
#pragma unroll
  for (int it = 0; it < 16; ++it) {
    const int oo = (t >> 6) * 16 + it;
    const float mean = sums[oo] * (1.0f / 32768.0f);
    const float var = sumsq[oo] * (1.0f / 32768.0f) - mean * mean;
    const float sc = gamma[oo] / sqrtf(var + 1e-5f);
    const float hv = tile[j][oo];
    const float hn = (hv - mean) * sc + beta[oo];
    const float g = 0.5f * hn * (1.0f + erff(hn * 0.70710678118654752f));
    out[((size_t)(b * 64 + oo)) * 4096 + n0 + j] = g;
  }
}

extern "C" void kernel_launch(void* const* d_in, const int* in_sizes, int n_in,
                              void* d_out, int out_size, void* d_ws, size_t ws_size,
                              hipStream_t stream) {
  const float* x = (const float*)d_in[0];
  const float* w = (const float*)d_in[1];
  const float* gamma = (const float*)d_in[2];
  const float* beta = (const float*)d_in[3];
  float* out = (float*)d_out;

  float* sq_ws = (float*)d_ws;               // 32768
  float* y_ws = sq_ws + 32768;               // 8 MB
  float* delta_ws = y_ws + 2097152;          // 8 MB
  float* h_ws = delta_ws + 2097152;          // 8 MB
  int* idx_ws = (int*)(h_ws + 2097152);      // 2.6 MB
  float* sums = (float*)(idx_ws + 655360);   // 64
  float* sumsq = sums + 64;                  // 64

  hipMemsetAsync(sums, 0, 2 * 64 * sizeof(float), stream);
  k1_pre<<<512, 256, 0, stream>>>(x, w, sq_ws, y_ws, delta_ws);
  k2_knn<<<512, 256, 0, stream>>>(x, sq_ws, idx_ws);
  k3_gather<<<512, 256, 0, stream>>>(y_ws, delta_ws, idx_ws, h_ws, sums, sumsq);
  k4_bn<<<512, 256, 0, stream>>>(h_ws, sums, sumsq, gamma, beta, out);
}

// Round 3
// 346.940 us; speedup vs baseline: 2.2801x; 1.4289x over previous
//
#include <hip/hip_runtime.h>

#define BIGF 3.402823466e38f

typedef __attribute__((ext_vector_type(8))) short bf16x8;
typedef __attribute__((ext_vector_type(4))) float f32x4;

__device__ __forceinline__ void gload_lds16(const float* g, float* lds) {
  __builtin_amdgcn_global_load_lds((const __attribute__((address_space(1))) void*)g,
                                   (__attribute__((address_space(3))) void*)lds, 16, 0, 0);
}
__device__ __forceinline__ void gload_lds16u(const unsigned short* g, unsigned short* lds) {
  __builtin_amdgcn_global_load_lds((const __attribute__((address_space(1))) void*)g,
                                   (__attribute__((address_space(3))) void*)lds, 16, 0, 0);
}

__device__ __forceinline__ unsigned short bf16_rne(float f) {
  unsigned int u = __float_as_uint(f);
  return (unsigned short)((u + 0x7fffu + ((u >> 16) & 1u)) >> 16);
}

// ---------------- K1: transpose + sq + y + delta + bf16 hi/lo packed rows ----------------
// xhl row (per point): 128 bf16 = [hi d0..63 | lo d0..63], stored as 16 chunks of 16B with
// chunk c placed at position c ^ (point&7) (bank-decorrelating swizzle, low-3-bit XOR).
__global__ __launch_bounds__(256) void k1_pre(const float* __restrict__ x, const float* __restrict__ w,
                                              float* __restrict__ sq, float* __restrict__ y,
                                              float* __restrict__ delta, unsigned short* __restrict__ xhl) {
  __shared__ __align__(16) float xt[64][68];
  __shared__ __align__(16) float ws[128][64];
  const int t = threadIdx.x;
  const int bid = blockIdx.x;
  const int b = bid >> 6;
  const int n0 = (bid & 63) << 6;
  const float* xb = x + (size_t)b * 64 * 4096;

#pragma unroll
  for (int rep = 0; rep < 16; ++rep) {
    int id = rep * 256 + t;
    int d = id >> 6, n = id & 63;
    xt[n][d] = xb[(size_t)d * 4096 + n0 + n];
  }
#pragma unroll
  for (int rep = 0; rep < 32; ++rep) {
    int id = rep * 256 + t;
    int u = id >> 6, dd = id & 63;
    ws[u][dd] = w[(u & 63) * 128 + ((u >> 6) << 6) + dd];
  }
  __syncthreads();

  // ---- bf16 hi/lo packed emit: thread t -> point p = t>>2, chunk group cg = t&3 ----
  {
    const int p = t >> 2;
    const int cg = t & 3;
    uint4* orow = (uint4*)xhl + ((size_t)(b << 12) + n0 + p) * 16;
#pragma unroll
    for (int cc = 0; cc < 4; ++cc) {
      const int c = cg * 4 + cc;
      const int kb = (c & 7) * 8;
      const bool lohalf = (c >= 8);
      unsigned int pk[4];
#pragma unroll
      for (int j2 = 0; j2 < 4; ++j2) {
        unsigned short u0, u1;
#pragma unroll
        for (int e = 0; e < 2; ++e) {
          const float xv = xt[p][kb + j2 * 2 + e];
          unsigned short h = bf16_rne(xv);
          unsigned short r;
          if (!lohalf) r = h;
          else r = bf16_rne(xv - __uint_as_float(((unsigned int)h) << 16));
          if (e == 0) u0 = r; else u1 = r;
        }
        pk[j2] = (unsigned int)u0 | ((unsigned int)u1 << 16);
      }
      uint4 v;
      v.x = pk[0]; v.y = pk[1]; v.z = pk[2]; v.w = pk[3];
      orow[c ^ (p & 7)] = v;
    }
  }

  const int p = t & 63;
  const int oc = t >> 6;
  float accy[16], accz[16];
#pragma unroll
  for (int j = 0; j < 16; ++j) { accy[j] = 0.f; accz[j] = 0.f; }

#pragma unroll 4
  for (int d4 = 0; d4 < 16; ++d4) {
    const float4 xv = *(const float4*)&xt[p][d4 * 4];
#pragma unroll
    for (int j = 0; j < 16; ++j) {
      const int o = oc * 16 + j;
      const float4 wy = *(const float4*)&ws[o][d4 * 4];
      const float4 wz = *(const float4*)&ws[o + 64][d4 * 4];
      accy[j] = fmaf(xv.x, wy.x, fmaf(xv.y, wy.y, fmaf(xv.z, wy.z, fmaf(xv.w, wy.w, accy[j]))));
      accz[j] = fmaf(xv.x, wz.x, fmaf(xv.y, wz.y, fmaf(xv.z, wz.z, fmaf(xv.w, wz.w, accz[j]))));
    }
  }

  if (oc == 0) {
    float s = 0.f;
#pragma unroll
    for (int d4 = 0; d4 < 16; ++d4) {
      const float4 v = *(const float4*)&xt[p][d4 * 4];
      s = fmaf(v.x, v.x, fmaf(v.y, v.y, fmaf(v.z, v.z, fmaf(v.w, v.w, s))));
    }
    sq[b * 4096 + n0 + p] = s;
  }

  const size_t row = ((size_t)b * 4096 + n0 + p) * 64 + oc * 16;
#pragma unroll
  for (int j4 = 0; j4 < 4; ++j4) {
    float4 yv = make_float4(accy[j4 * 4], accy[j4 * 4 + 1], accy[j4 * 4 + 2], accy[j4 * 4 + 3]);
    float4 dv = make_float4(accz[j4 * 4] - accy[j4 * 4], accz[j4 * 4 + 1] - accy[j4 * 4 + 1],
                            accz[j4 * 4 + 2] - accy[j4 * 4 + 2], accz[j4 * 4 + 3] - accy[j4 * 4 + 3]);
    *(float4*)&y[row + j4 * 4] = yv;
    *(float4*)&delta[row + j4 * 4] = dv;
  }
}

// ---------------- K2: MFMA pairwise-distance GEMM (bf16 hi/lo) + streaming top-20 ----------------
// block = 256 thr (4 waves), 64-point n-tile. n-side fragments register-resident across
// all 32 m-tiles. Per wave per kt: stage 8KB m-rows (global_load_lds x8) -> 8 A-frag
// ds_read_b128 -> 48 MFMAs (hi*hi + hi*lo + lo*hi) -> dump sq_m-2dot into scan buffer
// (overlays m-stage) -> scan + accept-buffer + rare drains. No barriers in main loop.
__global__ __launch_bounds__(256, 2) void k2_knn(const unsigned short* __restrict__ xhl,
                                                 const float* __restrict__ sq,
                                                 int* __restrict__ idx_out) {
  // As 16KB (4096 f) + 4 x 8KB wave slices (8192 f) + 4 x 6656B accept buffers (6656 f)
  __shared__ __align__(16) float smem[4096 + 8192 + 6656];
  const int t = threadIdx.x;
  const int lane = t & 63;
  const int w = t >> 6;
  float* BsW = smem + 4096 + (w << 11);
  uint4* BsW4 = (uint4*)BsW;
  const uint4* As4 = (const uint4*)smem;
  uint2* bufL = (uint2*)(smem + 12288) + ((w << 6) + lane) * 13;  // stride 13 (conflict-free)

  const int bid = blockIdx.x;
  const int b = bid >> 6;
  const int n0 = (bid & 63) << 6;
  const int pn = lane & 15, q = lane >> 4;

  const unsigned short* xr = xhl + ((size_t)(b << 12)) * 128;
  const float* sqb = sq + (b << 12);

  // stage A rows (64 points x 256B = 16KB): 16 x 1KB, 4 per wave
  {
    unsigned short* asu = (unsigned short*)smem;
#pragma unroll
    for (int qq = 0; qq < 4; ++qq) {
      const int kk = w * 4 + qq;
      gload_lds16u(xr + (size_t)n0 * 128 + kk * 512 + lane * 8, asu + kk * 512);
    }
  }
  __syncthreads();

  // n-side fragments, register-resident: per nt: [hi0, hi1, lo0, lo1]
  bf16x8 bfr[4][4];
#pragma unroll
  for (int nt = 0; nt < 4; ++nt)
#pragma unroll
    for (int j = 0; j < 4; ++j)
      bfr[nt][j] = *reinterpret_cast<const bf16x8*>(&As4[((nt << 4) + pn) * 16 + (((j << 2) + q) ^ (pn & 7))]);

  float kd[20];
  int ki[20];
#pragma unroll
  for (int s = 0; s < 20; ++s) { kd[s] = BIGF; ki[s] = -1; }
  const float sqn = sqb[n0 + lane];
  const int myn = lane;
  const int swz = myn & 7;
  int cnt = 0;

  auto ins = [&](float vd, int vi) {
#pragma unroll
    for (int s = 0; s < 20; ++s) {
      const float od = kd[s];
      const int oi = ki[s];
      const bool lt = vd < od;
      kd[s] = lt ? vd : od;
      ki[s] = lt ? vi : oi;
      vd = lt ? od : vd;
      vi = lt ? oi : vi;
    }
  };

  auto drain = [&]() {
#pragma unroll 1
    for (int j = 0; j < 12; ++j) {
      if (!__any(j < cnt)) break;
      if (j < cnt) {
        const uint2 e = bufL[j];
        const float dv = __uint_as_float(e.x);
        if (dv < kd[19]) ins(dv, (int)e.y);
      }
    }
    cnt = 0;
  };

  const f32x4 zero4 = {0.f, 0.f, 0.f, 0.f};
  f32x4 acc[4][2];
#pragma unroll
  for (int nt = 0; nt < 4; ++nt) { acc[nt][0] = zero4; acc[nt][1] = zero4; }

  for (int kt = 0; kt < 32; ++kt) {
    const int mbase = (w + 4 * kt) << 5;
    // stage m rows (32 points x 256B = 8KB): 8 x 1KB
    {
      unsigned short* bsu = (unsigned short*)BsW;
      const unsigned short* src = xr + (size_t)mbase * 128;
#pragma unroll
      for (int k = 0; k < 8; ++k) gload_lds16u(src + k * 512 + lane * 8, bsu + k * 512);
    }
    const f32x4 sqm0 = *(const f32x4*)&sqb[mbase + (q << 2)];
    const f32x4 sqm1 = *(const f32x4*)&sqb[mbase + 16 + (q << 2)];
    __builtin_amdgcn_s_waitcnt(0x0F70);  // vmcnt(0)

#pragma unroll
    for (int mt = 0; mt < 2; ++mt) {
      bf16x8 afr[4];
#pragma unroll
      for (int j = 0; j < 4; ++j)
        afr[j] = *reinterpret_cast<const bf16x8*>(&BsW4[((mt << 4) + pn) * 16 + (((j << 2) + q) ^ (pn & 7))]);
#pragma unroll
      for (int nt = 0; nt < 4; ++nt) {
        f32x4 a = acc[nt][mt];
        a = __builtin_amdgcn_mfma_f32_16x16x32_bf16(afr[0], bfr[nt][0], a, 0, 0, 0);  // hi_m*hi_n
        a = __builtin_amdgcn_mfma_f32_16x16x32_bf16(afr[1], bfr[nt][1], a, 0, 0, 0);
        a = __builtin_amdgcn_mfma_f32_16x16x32_bf16(afr[0], bfr[nt][2], a, 0, 0, 0);  // hi_m*lo_n
        a = __builtin_amdgcn_mfma_f32_16x16x32_bf16(afr[1], bfr[nt][3], a, 0, 0, 0);
        a = __builtin_amdgcn_mfma_f32_16x16x32_bf16(afr[2], bfr[nt][0], a, 0, 0, 0);  // lo_m*hi_n
        a = __builtin_amdgcn_mfma_f32_16x16x32_bf16(afr[3], bfr[nt][1], a, 0, 0, 0);
        acc[nt][mt] = a;
      }
    }

    // dump: value = sq_m - 2*dot, row n, m-quad g=(mt*4+q) at chunk g^(n&7)
#pragma unroll
    for (int nt = 0; nt < 4; ++nt) {
#pragma unroll
      for (int mt = 0; mt < 2; ++mt) {
        const int n = (nt << 4) + pn;
        const int g = (mt << 2) + q;
        const int pc = g ^ (n & 7);
        const f32x4 sv = mt ? sqm1 : sqm0;
        f32x4 dv = sv - 2.0f * acc[nt][mt];
        *(f32x4*)&BsW[(n << 5) + (pc << 2)] = dv;
        acc[nt][mt] = zero4;
      }
    }

    // scan own row (myn): 8 chunks of 4, min4 pre-gate, accepts -> LDS buffer
#pragma unroll 1
    for (int cc = 0; cc < 8; ++cc) {
      const float4 v = *(const float4*)&BsW[(myn << 5) + ((cc ^ swz) << 2)];
      const int mb = mbase + (cc << 2);
      const float c0 = sqn + v.x, c1 = sqn + v.y, c2 = sqn + v.z, c3 = sqn + v.w;
      const float thr = kd[19];
      const float mn = fminf(fminf(c0, c1), fminf(c2, c3));
      if (mn < thr) {
        if (c0 < thr) { bufL[cnt] = make_uint2(__float_as_uint(c0), (unsigned)mb); cnt++; }
        if (c1 < thr) { bufL[cnt] = make_uint2(__float_as_uint(c1), (unsigned)(mb + 1)); cnt++; }
        if (c2 < thr) { bufL[cnt] = make_uint2(__float_as_uint(c2), (unsigned)(mb + 2)); cnt++; }
        if (c3 < thr) { bufL[cnt] = make_uint2(__float_as_uint(c3), (unsigned)(mb + 3)); cnt++; }
      }
      if (__any(cnt > 8)) drain();
    }
  }
  drain();

  // merge the 4 waves' partial lists (LDS overlay on smem)
  __syncthreads();
  float* pf = smem;                 // [4][20][64]
  int* pi = (int*)(smem + 5120);    // [4][20][64]
#pragma unroll
  for (int s = 0; s < 20; ++s) {
    pf[(w * 20 + s) * 64 + lane] = kd[s];
    pi[(w * 20 + s) * 64 + lane] = ki[s];
  }
  __syncthreads();
  if (w == 0) {
    auto insTie = [&](float vd, int vi) {
#pragma unroll
      for (int s = 0; s < 20; ++s) {
        const float od = kd[s];
        const int oi = ki[s];
        const bool lt = (vd < od) || (vd == od && vi < oi);
        kd[s] = lt ? vd : od;
        ki[s] = lt ? vi : oi;
        vd = lt ? od : vd;
        vi = lt ? oi : vi;
      }
    };
    for (int ww = 1; ww < 4; ++ww) {
#pragma unroll 1
      for (int s = 0; s < 20; ++s) {
        const float dv = pf[(ww * 20 + s) * 64 + lane];
        const int iv = pi[(ww * 20 + s) * 64 + lane];
        if (dv < kd[19] || (dv == kd[19] && iv < ki[19])) insTie(dv, iv);
      }
    }
    int* orow = idx_out + ((size_t)(b << 12) + n0 + lane) * 20;
#pragma unroll
    for (int s = 0; s < 20; ++s) orow[s] = ki[s];
  }
}

// ---------------- K3: gathered neighbor max + h + BN stats ----------------
__global__ __launch_bounds__(256) void k3_gather(const float* __restrict__ y,
                                                 const float* __restrict__ delta,
                                                 const int* __restrict__ idx,
                                                 float* __restrict__ h,
                                                 float* __restrict__ sums,
                                                 float* __restrict__ sumsq) {
  const int t = threadIdx.x;
  const int lane = t & 63;  // channel o
  const int w = t >> 6;
  const int blk = blockIdx.x;
  float s1 = 0.f, s2 = 0.f;
  for (int p = 0; p < 16; ++p) {
    const int ng = blk * 64 + w * 16 + p;
    const int b = ng >> 12;
    const int* row = idx + (size_t)ng * 20;
    float mx = -BIGF;
#pragma unroll
    for (int kk = 0; kk < 20; ++kk) {
      const int nbr = row[kk];
      mx = fmaxf(mx, y[((size_t)(b << 12) + nbr) * 64 + lane]);
    }
    const float hv = mx + delta[(size_t)ng * 64 + lane];
    h[(size_t)ng * 64 + lane] = hv;
    s1 += hv;
    s2 += hv * hv;
  }
  __shared__ float r1[4][64], r2[4][64];
  r1[w][lane] = s1;
  r2[w][lane] = s2;
  __syncthreads();
  if (w == 0) {
    const float a = r1[0][lane] + r1[1][lane] + r1[2][lane] + r1[3][lane];
    const float c = r2[0][lane] + r2[1][lane] + r2[2][lane] + r2[3][lane];
    atomicAdd(&sums[lane], a);
    atomicAdd(&sumsq[lane], c);
  }
}

// ---------------- K4: BN finalize + exact GELU + transposed write ----------------
__global__ __launch_bounds__(256) void k4_bn(const float* __restrict__ h,
                                             const float* __restrict__ sums,
                                             const float* __restrict__ sumsq,
                                             const float* __restrict__ gamma,
                                             const float* __restrict__ beta,
                                             float* __restrict__ out) {
  __shared__ float tile[64][65];
  const int bid = blockIdx.x;
  const int b = bid >> 6;
  const int n0 = (bid & 63) << 6;
  const int t = threadIdx.x;
  const int o = t & 63;
#pragma unroll
  for (int it = 0; it < 16; ++it) {
    const int n = (t >> 6) * 16 + it;
    tile[n][o] = h[(((size_t)b << 12) + n0 + n) * 64 + o];
  }
  __syncthreads();
  const int j = t & 63;
#pragma unroll
  for (int it = 0; it < 16; ++it) {
    const int oo = (t >> 6) * 16 + it;
    const float mean = sums[oo] * (1.0f / 32768.0f);
    const float var = sumsq[oo] * (1.0f / 32768.0f) - mean * mean;
    const float sc = gamma[oo] / sqrtf(var + 1e-5f);
    const float hv = tile[j][oo];
    const float hn = (hv - mean) * sc + beta[oo];
    const float g = 0.5f * hn * (1.0f + erff(hn * 0.70710678118654752f));
    out[((size_t)(b * 64 + oo)) * 4096 + n0 + j] = g;
  }
}

extern "C" void kernel_launch(void* const* d_in, const int* in_sizes, int n_in,
                              void* d_out, int out_size, void* d_ws, size_t ws_size,
                              hipStream_t stream) {
  const float* x = (const float*)d_in[0];
  const float* w = (const float*)d_in[1];
  const float* gamma = (const float*)d_in[2];
  const float* beta = (const float*)d_in[3];
  float* out = (float*)d_out;

  float* sq_ws = (float*)d_ws;               // 32768
  float* y_ws = sq_ws + 32768;               // 8 MB
  float* delta_ws = y_ws + 2097152;          // 8 MB
  float* h_ws = delta_ws + 2097152;          // 8 MB (k3/k4) — overlaid by xhl in k1/k2
  int* idx_ws = (int*)(h_ws + 2097152);      // 2.6 MB
  float* sums = (float*)(idx_ws + 655360);   // 64
  float* sumsq = sums + 64;                  // 64
  unsigned short* xhl = (unsigned short*)h_ws;  // 8 MB bf16 hi/lo rows (dead after k2)

  hipMemsetAsync(sums, 0, 2 * 64 * sizeof(float), stream);
  k1_pre<<<512, 256, 0, stream>>>(x, w, sq_ws, y_ws, delta_ws, xhl);
  k2_knn<<<512, 256, 0, stream>>>(xhl, sq_ws, idx_ws);
  k3_gather<<<512, 256, 0, stream>>>(y_ws, delta_ws, idx_ws, h_ws, sums, sumsq);
  k4_bn<<<512, 256, 0, stream>>>(h_ws, sums, sumsq, gamma, beta, out);
}